// Round 12
// baseline (331.145 us; speedup 1.0000x reference)
//
#include <hip/hip_runtime.h>

#define NNODES 50000
#define NF 256
#define NH 512
#define MPAD 50048   // 391 * 128
#define BN_EPS 1e-5f
#define SBLOCKS 512  // stats stage-1 blocks
#define NSCAN 196    // ceil(NNODES/256)

typedef unsigned short u16;
typedef __attribute__((ext_vector_type(8))) short bf16x8;
typedef __attribute__((ext_vector_type(4))) float f32x4;

__device__ __forceinline__ float bf2f(u16 u) {
  union { unsigned int i; float f; } v; v.i = ((unsigned int)u) << 16; return v.f;
}
__device__ __forceinline__ u16 f2bf(float f) {
  union { float ff; unsigned int i; } v; v.ff = f;
  unsigned int r = v.i + 0x7FFFu + ((v.i >> 16) & 1u);
  return (u16)(r >> 16);
}

__device__ __forceinline__ void async16(const void* g, void* l) {
  __builtin_amdgcn_global_load_lds(
      (const __attribute__((address_space(1))) unsigned int*)g,
      (__attribute__((address_space(3))) unsigned int*)l, 16, 0, 0);
}

// ---------------- edge-index dtype probe ----------------
// int64 little-endian with values in [0,50000): every odd dword is 0.
__global__ void detect_idx(const int* __restrict__ ei, int* __restrict__ flag) {
  int v = ei[2 * threadIdx.x + 1];
  unsigned long long b = __ballot(v == 0);
  if (threadIdx.x == 0) *flag = (b == ~0ull) ? 1 : 0;
}

// ---------------- xbf = bf16(x), halves gather payload ----------------
__global__ __launch_bounds__(256) void conv_x(const float* __restrict__ x,
                                              u16* __restrict__ xbf) {
  const size_t n8 = (size_t)NNODES * NF / 8;
  size_t stride = (size_t)gridDim.x * blockDim.x;
  for (size_t i = blockIdx.x * (size_t)blockDim.x + threadIdx.x; i < n8; i += stride) {
    float4 a = ((const float4*)x)[2 * i];
    float4 b = ((const float4*)x)[2 * i + 1];
    ushort4 lo, hi;
    lo.x = f2bf(a.x); lo.y = f2bf(a.y); lo.z = f2bf(a.z); lo.w = f2bf(a.w);
    hi.x = f2bf(b.x); hi.y = f2bf(b.y); hi.z = f2bf(b.z); hi.w = f2bf(b.w);
    ((ushort4*)xbf)[2 * i] = lo;
    ((ushort4*)xbf)[2 * i + 1] = hi;
  }
}

// ---------------- CSR build: histogram over dst ----------------
__global__ __launch_bounds__(256) void hist_kernel(const int* __restrict__ ei,
                                                   const int* __restrict__ flag,
                                                   int* __restrict__ deg, int E) {
  const int is64 = *flag;
  int stride = gridDim.x * blockDim.x;
  for (int e = blockIdx.x * blockDim.x + threadIdx.x; e < E; e += stride) {
    int dst = is64 ? ei[2 * E + 2 * e] : ei[E + e];
    if ((unsigned)dst < NNODES) atomicAdd(&deg[dst], 1);
  }
}

// ---------------- CSR build: 3-phase parallel exclusive scan ----------------
__global__ __launch_bounds__(256) void scan1_kernel(const int* __restrict__ deg,
                                                    int* __restrict__ rowptr,
                                                    int* __restrict__ blocksums) {
  const int t = threadIdx.x;
  int i = blockIdx.x * 256 + t;
  int v = (i < NNODES) ? deg[i] : 0;
  __shared__ int sm[256];
  sm[t] = v;
  __syncthreads();
  for (int off = 1; off < 256; off <<= 1) {
    int u = (t >= off) ? sm[t - off] : 0;
    __syncthreads();
    sm[t] += u;
    __syncthreads();
  }
  if (i < NNODES) rowptr[i] = sm[t] - v;            // exclusive within block
  if (t == 255) blocksums[blockIdx.x] = sm[255];    // block total
}

__global__ __launch_bounds__(256) void scan2_kernel(int* __restrict__ blocksums,
                                                    int* __restrict__ rowptr) {
  const int t = threadIdx.x;
  int v = (t < NSCAN) ? blocksums[t] : 0;
  __shared__ int sm[256];
  sm[t] = v;
  __syncthreads();
  for (int off = 1; off < 256; off <<= 1) {
    int u = (t >= off) ? sm[t - off] : 0;
    __syncthreads();
    sm[t] += u;
    __syncthreads();
  }
  if (t < NSCAN) blocksums[t] = sm[t] - v;          // exclusive block offsets
  if (t == 255) rowptr[NNODES] = sm[255];           // total == E
}

__global__ __launch_bounds__(256) void scan3_kernel(const int* __restrict__ blocksums,
                                                    int* __restrict__ rowptr) {
  int i = blockIdx.x * 256 + threadIdx.x;
  if (i < NNODES) rowptr[i] += blocksums[blockIdx.x];
}

// ---------------- CSR build: fill src lists ----------------
__global__ __launch_bounds__(256) void fill_kernel(const int* __restrict__ ei,
                                                   const int* __restrict__ flag,
                                                   const int* __restrict__ rowptr,
                                                   int* __restrict__ cursor,
                                                   int* __restrict__ srcs, int E) {
  const int is64 = *flag;
  int stride = gridDim.x * blockDim.x;
  for (int e = blockIdx.x * blockDim.x + threadIdx.x; e < E; e += stride) {
    int src, dst;
    if (is64) { src = ei[2 * e]; dst = ei[2 * E + 2 * e]; }
    else      { src = ei[e];     dst = ei[E + e]; }
    if ((unsigned)src >= NNODES || (unsigned)dst >= NNODES) continue;
    int pos = rowptr[dst] + atomicAdd(&cursor[dst], 1);
    if ((unsigned)pos < (unsigned)E) srcs[pos] = src;   // bounds insurance
  }
}

// ---------------- gather-reduce: hpad[n] = bf16(x[n] + sum_{j in N(n)} x[j]) ----------------
// One wave per node; lane l owns feats [4l..4l+3] (8B of bf16). Pad rows -> 0.
__global__ __launch_bounds__(256) void gather_kernel(const u16* __restrict__ xbf,
                                                     const int* __restrict__ srcs,
                                                     const int* __restrict__ rowptr,
                                                     u16* __restrict__ hpad) {
  const int lane = threadIdx.x & 63;
  const int node = blockIdx.x * 4 + (threadIdx.x >> 6);
  if (node >= MPAD) return;
  ushort4* outp = (ushort4*)(hpad + (size_t)node * NF + lane * 4);
  if (node >= NNODES) {
    ushort4 z = {0, 0, 0, 0};
    *outp = z;
    return;
  }
  ushort4 sv = ((const ushort4*)(xbf + (size_t)node * NF))[lane];
  float4 acc;
  acc.x = bf2f(sv.x); acc.y = bf2f(sv.y); acc.z = bf2f(sv.z); acc.w = bf2f(sv.w);
  int e = rowptr[node];
  const int e1 = rowptr[node + 1];
  for (; e + 3 < e1; e += 4) {
    int s0 = srcs[e], s1 = srcs[e + 1], s2 = srcs[e + 2], s3 = srcs[e + 3];
    ushort4 v0 = ((const ushort4*)(xbf + (size_t)s0 * NF))[lane];
    ushort4 v1 = ((const ushort4*)(xbf + (size_t)s1 * NF))[lane];
    ushort4 v2 = ((const ushort4*)(xbf + (size_t)s2 * NF))[lane];
    ushort4 v3 = ((const ushort4*)(xbf + (size_t)s3 * NF))[lane];
    acc.x += bf2f(v0.x) + bf2f(v1.x) + bf2f(v2.x) + bf2f(v3.x);
    acc.y += bf2f(v0.y) + bf2f(v1.y) + bf2f(v2.y) + bf2f(v3.y);
    acc.z += bf2f(v0.z) + bf2f(v1.z) + bf2f(v2.z) + bf2f(v3.z);
    acc.w += bf2f(v0.w) + bf2f(v1.w) + bf2f(v2.w) + bf2f(v3.w);
  }
  for (; e < e1; ++e) {
    int s0 = srcs[e];
    ushort4 v0 = ((const ushort4*)(xbf + (size_t)s0 * NF))[lane];
    acc.x += bf2f(v0.x); acc.y += bf2f(v0.y); acc.z += bf2f(v0.z); acc.w += bf2f(v0.w);
  }
  ushort4 o;
  o.x = f2bf(acc.x); o.y = f2bf(acc.y); o.z = f2bf(acc.z); o.w = f2bf(acc.w);
  *outp = o;
}

// ---------------- W1t[n][k] = bf16(W1[k][n]), f32 source ----------------
__global__ __launch_bounds__(256) void transpose_w1(const float* __restrict__ W1,
                                                    u16* __restrict__ W1t) {
  int idx = blockIdx.x * 256 + threadIdx.x;   // 512*256 total
  int n = idx >> 8;
  int k = idx & 255;
  W1t[(size_t)n * NF + k] = f2bf(W1[(size_t)k * NH + n]);
}

// ---------------- GEMM: C[M][512] = A[M][K] * Bt[512][K]^T + bias ----------------
// T3 2-phase: double-buffered LDS, next-tile global_load_lds issued BEFORE the
// current tile's MFMA so HBM latency hides under compute. Pre-swizzled source +
// swizzled ds_read (bank-conflict-free, rule #21). m204 XCD chunking, col-fastest.
template <int K, bool RELU, bool OUTF32>
__global__ __launch_bounds__(256) void gemm_bt(const u16* __restrict__ Ab,
                                               const u16* __restrict__ Bt,
                                               const float* __restrict__ bias,
                                               void* __restrict__ Cp, int Mstore) {
  __shared__ __align__(16) u16 As[2][128 * 64];
  __shared__ __align__(16) u16 Bs[2][128 * 64];
  const int tid = threadIdx.x;
  const int lane = tid & 63;
  const int wid = tid >> 6;
  const int wr = wid >> 1, wc = wid & 1;

  // m204 bijective XCD-chunked swizzle
  const int nwg = gridDim.x;
  const int q = nwg >> 3, r = nwg & 7;
  const int xcd = blockIdx.x & 7, idx = blockIdx.x >> 3;
  const int work = (xcd < r ? xcd * (q + 1) : r * (q + 1) + (xcd - r) * q) + idx;
  const int brow = (work >> 2) * 128;   // col-fastest: same-A blocks adjacent
  const int bcol = (work & 3) * 128;

  f32x4 acc[4][4] = {};

  // gload_lds lane mapping: lane l -> LDS element chunkbase + l*8
  //   row-in-chunk = l>>3, swizzled k-slot cs = l&7 -> global kc = (cs ^ row&7)*8
  const int lrow = lane >> 3;
  const int lkc = ((lane & 7) ^ (lrow & 7)) * 8;

  const int nt = K / 64;

  // prologue: stage tile 0 into buffer 0
#pragma unroll
  for (int i = 0; i < 4; ++i) {
    int c = i * 4 + wid;
    int row = c * 8 + lrow;
    async16(Ab + (size_t)(brow + row) * K + lkc, &As[0][c * 512]);
    async16(Bt + (size_t)(bcol + row) * K + lkc, &Bs[0][c * 512]);
  }
  __syncthreads();

  int cur = 0;
  for (int t = 0; t < nt; ++t) {
    // issue next tile's loads FIRST (into the other buffer) — overlap with MFMA
    if (t + 1 < nt) {
      const int k0 = (t + 1) * 64;
#pragma unroll
      for (int i = 0; i < 4; ++i) {
        int c = i * 4 + wid;
        int row = c * 8 + lrow;
        async16(Ab + (size_t)(brow + row) * K + k0 + lkc, &As[cur ^ 1][c * 512]);
        async16(Bt + (size_t)(bcol + row) * K + k0 + lkc, &Bs[cur ^ 1][c * 512]);
      }
    }
    // compute current tile
#pragma unroll
    for (int ks = 0; ks < 2; ++ks) {
      bf16x8 af[4], bfr[4];
      const int rchunk = ((ks << 2) + (lane >> 4)) ^ (lane & 7);  // swizzled read slot
#pragma unroll
      for (int m = 0; m < 4; ++m)
        af[m] = *(const bf16x8*)&As[cur][(wr * 64 + m * 16 + (lane & 15)) * 64 + rchunk * 8];
#pragma unroll
      for (int n = 0; n < 4; ++n)
        bfr[n] = *(const bf16x8*)&Bs[cur][(wc * 64 + n * 16 + (lane & 15)) * 64 + rchunk * 8];
#pragma unroll
      for (int m = 0; m < 4; ++m)
#pragma unroll
        for (int n = 0; n < 4; ++n)
          acc[m][n] = __builtin_amdgcn_mfma_f32_16x16x32_bf16(af[m], bfr[n], acc[m][n], 0, 0, 0);
    }
    __syncthreads();   // drains prefetch vmcnt + all ds_reads; next iter flips buffers
    cur ^= 1;
  }

#pragma unroll
  for (int n = 0; n < 4; ++n) {
    int col = bcol + wc * 64 + n * 16 + (lane & 15);
    float bv2 = bias[col];
#pragma unroll
    for (int m = 0; m < 4; ++m) {
      int row0 = brow + wr * 64 + m * 16 + ((lane >> 4) << 2);
#pragma unroll
      for (int r2 = 0; r2 < 4; ++r2) {
        float v = acc[m][n][r2] + bv2;
        if (RELU) v = v > 0.f ? v : 0.f;
        int row = row0 + r2;
        if (row < Mstore) {
          if (OUTF32) ((float*)Cp)[(size_t)row * NH + col] = v;
          else        ((u16*)Cp)[(size_t)row * NH + col] = f2bf(v);
        }
      }
    }
  }
}

// ---------------- stats stage 1: per-block column sums/sumsq, NO atomics ----------------
// partials[b][c]: c in [0,512) = sum, c in [512,1024) = sumsq.
__global__ __launch_bounds__(256) void stats1_kernel(const u16* __restrict__ h1,
                                                     float* __restrict__ partials) {
  const int tg = threadIdx.x & 63;     // column group: cols [8*tg, 8*tg+8)
  const int tr = threadIdx.x >> 6;     // row phase 0..3
  float s[8] = {}, q[8] = {};
  for (int r = blockIdx.x * 4 + tr; r < NNODES; r += SBLOCKS * 4) {
    bf16x8 v = *(const bf16x8*)(h1 + (size_t)r * NH + tg * 8);
#pragma unroll
    for (int j = 0; j < 8; ++j) {
      float f = bf2f((u16)v[j]);
      s[j] += f; q[j] += f * f;
    }
  }
  __shared__ float red_s[4][512];
  __shared__ float red_q[4][512];
#pragma unroll
  for (int j = 0; j < 8; ++j) {
    red_s[tr][tg * 8 + j] = s[j];
    red_q[tr][tg * 8 + j] = q[j];
  }
  __syncthreads();
  float* outp = partials + (size_t)blockIdx.x * 1024;
#pragma unroll
  for (int h = 0; h < 2; ++h) {
    int c = threadIdx.x + h * 256;
    outp[c]       = red_s[0][c] + red_s[1][c] + red_s[2][c] + red_s[3][c];
    outp[c + 512] = red_q[0][c] + red_q[1][c] + red_q[2][c] + red_q[3][c];
  }
}

// ---------------- stats stage 2: reduce partials over blocks (plain stores) ----------------
__global__ __launch_bounds__(256) void stats2_kernel(const float* __restrict__ partials,
                                                     float* __restrict__ ssum) {
  int c = blockIdx.x * 256 + threadIdx.x;   // 0..1023
  float acc = 0.f;
  for (int b = 0; b < SBLOCKS; ++b) acc += partials[(size_t)b * 1024 + c];
  ssum[c] = acc;
}

// ---------------- BN finalize + sanity check ----------------
__global__ void bn_finalize(const float* __restrict__ ssum, const float* __restrict__ ssq,
                            const float* __restrict__ gamma, const float* __restrict__ beta,
                            float* __restrict__ a_arr, float* __restrict__ c_arr,
                            int* __restrict__ err) {
  int c = threadIdx.x;  // 512 threads
  float mean = ssum[c] * (1.f / NNODES);
  float var = ssq[c] * (1.f / NNODES) - mean * mean;
  if (!(mean == mean) || !(var == var) ||
      fabsf(mean) > 1e20f || var > 1e20f || var < -1e-2f)
    err[0] = 2;
  unsigned long long z = __ballot(ssq[c] == 0.0f);
  if (threadIdx.x == 0 && z == ~0ull) err[1] = 3;
  if (var < 0.f) var = 0.f;
  float a = gamma[c] * rsqrtf(var + BN_EPS);
  a_arr[c] = a;
  c_arr[c] = beta[c] - mean * a;
}

// ---------------- fold BN into W2 ----------------
__global__ __launch_bounds__(256) void fold_w2(const float* __restrict__ W2,
                                               const float* __restrict__ b2,
                                               const float* __restrict__ a_arr,
                                               const float* __restrict__ c_arr,
                                               u16* __restrict__ W2pt,
                                               float* __restrict__ bias2p) {
  int n = blockIdx.x;
  int t = threadIdx.x;
  float accv = 0.f;
  for (int k = t; k < NH; k += 256) {
    float w = W2[(size_t)k * NH + n];
    W2pt[(size_t)n * NH + k] = f2bf(a_arr[k] * w);
    accv += c_arr[k] * w;
  }
  __shared__ float red[256];
  red[t] = accv;
  __syncthreads();
  for (int s = 128; s > 0; s >>= 1) {
    if (t < s) red[t] += red[t + s];
    __syncthreads();
  }
  if (t == 0) bias2p[n] = b2[n] + red[0];
}

// ---------------- diagnostics ----------------
__global__ __launch_bounds__(256) void write_sentinel(float* __restrict__ out, int n, float val) {
  int stride = gridDim.x * blockDim.x;
  for (int i = blockIdx.x * blockDim.x + threadIdx.x; i < n; i += stride) out[i] = val;
}

__global__ __launch_bounds__(256) void apply_err(const int* __restrict__ err,
                                                 float* __restrict__ out, int n) {
  float val = 0.f;
  if (err[1] == 3) val = -300000.f;
  if (err[0] == 2) val = -500000.f;
  if (val == 0.f) return;
  int stride = gridDim.x * blockDim.x;
  for (int i = blockIdx.x * blockDim.x + threadIdx.x; i < n; i += stride) out[i] = val;
}

extern "C" void kernel_launch(void* const* d_in, const int* in_sizes, int n_in,
                              void* d_out, int out_size, void* d_ws, size_t ws_size,
                              hipStream_t stream) {
  const float* x     = (const float*)d_in[0];
  const int*   ei    = (const int*)d_in[1];
  const float* W1    = (const float*)d_in[2];
  const float* b1    = (const float*)d_in[3];
  const float* gamma = (const float*)d_in[4];
  const float* beta  = (const float*)d_in[5];
  const float* W2    = (const float*)d_in[6];
  const float* b2    = (const float*)d_in[7];
  float* out = (float*)d_out;
  const int E = in_sizes[1] / 2;   // 800000

  char* ws = (char*)d_ws;
  size_t off = 0;
  auto alloc = [&](size_t bytes) {
    char* p = ws + off;
    off += (bytes + 255) & ~(size_t)255;
    return p;
  };
  u16*   xbf    = (u16*)alloc((size_t)NNODES * NF * 2);     // 25.6 MB
  u16*   hpad   = (u16*)alloc((size_t)MPAD * NF * 2);       // 25.6 MB
  u16*   h1     = (u16*)alloc((size_t)MPAD * NH * 2);       // 51.25 MB
  u16*   W1t    = (u16*)alloc((size_t)NH * NF * 2);
  u16*   W2pt   = (u16*)alloc((size_t)NH * NH * 2);
  int*   srcs   = (int*)alloc((size_t)E * 4);               // 3.2 MB
  int*   rowptr = (int*)alloc((size_t)(NNODES + 1) * 4);
  int*   deg    = (int*)alloc((size_t)2 * NNODES * 4);      // deg[0:N] + cursor[N:2N], ONE block
  int*   cursor = deg + NNODES;
  int*   bsums  = (int*)alloc(256 * 4);                     // scan block sums
  float* parts  = (float*)alloc((size_t)SBLOCKS * 1024 * 4);// 2 MB stats partials
  float* ssum   = (float*)alloc(NH * 4);   // ssum+ssq contiguous (stats2 writes both)
  float* ssq    = (float*)alloc(NH * 4);
  int*   err    = (int*)alloc(8);
  float* a_arr  = (float*)alloc(NH * 4);
  float* c_arr  = (float*)alloc(NH * 4);
  float* bias2p = (float*)alloc(NH * 4);
  int*   flag   = (int*)alloc(4);

  if (off > ws_size) {
    write_sentinel<<<2048, 256, 0, stream>>>(out, out_size,
        1.0e7f + 1048576.0f * (float)(ws_size >> 20));
    return;
  }

  hipMemsetAsync(deg, 0, (size_t)2 * NNODES * 4, stream);   // deg + cursor (contiguous)
  hipMemsetAsync(err, 0, 8, stream);

  detect_idx<<<1, 64, 0, stream>>>(ei, flag);
  conv_x<<<2048, 256, 0, stream>>>(x, xbf);
  hist_kernel<<<1024, 256, 0, stream>>>(ei, flag, deg, E);
  scan1_kernel<<<NSCAN, 256, 0, stream>>>(deg, rowptr, bsums);
  scan2_kernel<<<1, 256, 0, stream>>>(bsums, rowptr);
  scan3_kernel<<<NSCAN, 256, 0, stream>>>(bsums, rowptr);
  fill_kernel<<<1024, 256, 0, stream>>>(ei, flag, rowptr, cursor, srcs, E);
  gather_kernel<<<MPAD / 4, 256, 0, stream>>>(xbf, srcs, rowptr, hpad);

  transpose_w1<<<512, 256, 0, stream>>>(W1, W1t);

  const int nwg = (MPAD / 128) * 4;   // 1564, 1-D grid (col-fastest + XCD chunking)
  gemm_bt<NF, true, false><<<nwg, 256, 0, stream>>>(hpad, W1t, b1, h1, MPAD);

  stats1_kernel<<<SBLOCKS, 256, 0, stream>>>(h1, parts);
  stats2_kernel<<<4, 256, 0, stream>>>(parts, ssum);
  bn_finalize<<<1, NH, 0, stream>>>(ssum, ssq, gamma, beta, a_arr, c_arr, err);
  fold_w2<<<NH, 256, 0, stream>>>(W2, b2, a_arr, c_arr, W2pt, bias2p);

  gemm_bt<NH, false, true><<<nwg, 256, 0, stream>>>(h1, W2pt, bias2p, out, NNODES);

  apply_err<<<2048, 256, 0, stream>>>(err, out, out_size);
}

// Round 13
// 309.018 us; speedup vs baseline: 1.0716x; 1.0716x over previous
//
#include <hip/hip_runtime.h>

#define NNODES 50000
#define NF 256
#define NH 512
#define MPAD 50048   // 391 * 128
#define BN_EPS 1e-5f
#define SBLOCKS 512  // stats stage-1 blocks
#define NSCAN 196    // ceil(NNODES/256)

typedef unsigned short u16;
typedef __attribute__((ext_vector_type(8))) short bf16x8;
typedef __attribute__((ext_vector_type(4))) float f32x4;

__device__ __forceinline__ float bf2f(u16 u) {
  union { unsigned int i; float f; } v; v.i = ((unsigned int)u) << 16; return v.f;
}
__device__ __forceinline__ u16 f2bf(float f) {
  union { float ff; unsigned int i; } v; v.ff = f;
  unsigned int r = v.i + 0x7FFFu + ((v.i >> 16) & 1u);
  return (u16)(r >> 16);
}

__device__ __forceinline__ void async16(const void* g, void* l) {
  __builtin_amdgcn_global_load_lds(
      (const __attribute__((address_space(1))) unsigned int*)g,
      (__attribute__((address_space(3))) unsigned int*)l, 16, 0, 0);
}

// ---------------- edge-index dtype probe ----------------
// int64 little-endian with values in [0,50000): every odd dword is 0.
__global__ void detect_idx(const int* __restrict__ ei, int* __restrict__ flag) {
  int v = ei[2 * threadIdx.x + 1];
  unsigned long long b = __ballot(v == 0);
  if (threadIdx.x == 0) *flag = (b == ~0ull) ? 1 : 0;
}

// ---------------- xbf = bf16(x), halves gather payload ----------------
__global__ __launch_bounds__(256) void conv_x(const float* __restrict__ x,
                                              u16* __restrict__ xbf) {
  const size_t n8 = (size_t)NNODES * NF / 8;
  size_t stride = (size_t)gridDim.x * blockDim.x;
  for (size_t i = blockIdx.x * (size_t)blockDim.x + threadIdx.x; i < n8; i += stride) {
    float4 a = ((const float4*)x)[2 * i];
    float4 b = ((const float4*)x)[2 * i + 1];
    ushort4 lo, hi;
    lo.x = f2bf(a.x); lo.y = f2bf(a.y); lo.z = f2bf(a.z); lo.w = f2bf(a.w);
    hi.x = f2bf(b.x); hi.y = f2bf(b.y); hi.z = f2bf(b.z); hi.w = f2bf(b.w);
    ((ushort4*)xbf)[2 * i] = lo;
    ((ushort4*)xbf)[2 * i + 1] = hi;
  }
}

// ---------------- CSR build: histogram over dst ----------------
__global__ __launch_bounds__(256) void hist_kernel(const int* __restrict__ ei,
                                                   const int* __restrict__ flag,
                                                   int* __restrict__ deg, int E) {
  const int is64 = *flag;
  int stride = gridDim.x * blockDim.x;
  for (int e = blockIdx.x * blockDim.x + threadIdx.x; e < E; e += stride) {
    int dst = is64 ? ei[2 * E + 2 * e] : ei[E + e];
    if ((unsigned)dst < NNODES) atomicAdd(&deg[dst], 1);
  }
}

// ---------------- CSR build: 3-phase parallel exclusive scan ----------------
__global__ __launch_bounds__(256) void scan1_kernel(const int* __restrict__ deg,
                                                    int* __restrict__ rowptr,
                                                    int* __restrict__ blocksums) {
  const int t = threadIdx.x;
  int i = blockIdx.x * 256 + t;
  int v = (i < NNODES) ? deg[i] : 0;
  __shared__ int sm[256];
  sm[t] = v;
  __syncthreads();
  for (int off = 1; off < 256; off <<= 1) {
    int u = (t >= off) ? sm[t - off] : 0;
    __syncthreads();
    sm[t] += u;
    __syncthreads();
  }
  if (i < NNODES) rowptr[i] = sm[t] - v;            // exclusive within block
  if (t == 255) blocksums[blockIdx.x] = sm[255];    // block total
}

__global__ __launch_bounds__(256) void scan2_kernel(int* __restrict__ blocksums,
                                                    int* __restrict__ rowptr) {
  const int t = threadIdx.x;
  int v = (t < NSCAN) ? blocksums[t] : 0;
  __shared__ int sm[256];
  sm[t] = v;
  __syncthreads();
  for (int off = 1; off < 256; off <<= 1) {
    int u = (t >= off) ? sm[t - off] : 0;
    __syncthreads();
    sm[t] += u;
    __syncthreads();
  }
  if (t < NSCAN) blocksums[t] = sm[t] - v;          // exclusive block offsets
  if (t == 255) rowptr[NNODES] = sm[255];           // total == E
}

__global__ __launch_bounds__(256) void scan3_kernel(const int* __restrict__ blocksums,
                                                    int* __restrict__ rowptr) {
  int i = blockIdx.x * 256 + threadIdx.x;
  if (i < NNODES) rowptr[i] += blocksums[blockIdx.x];
}

// ---------------- CSR build: fill src lists ----------------
__global__ __launch_bounds__(256) void fill_kernel(const int* __restrict__ ei,
                                                   const int* __restrict__ flag,
                                                   const int* __restrict__ rowptr,
                                                   int* __restrict__ cursor,
                                                   int* __restrict__ srcs, int E) {
  const int is64 = *flag;
  int stride = gridDim.x * blockDim.x;
  for (int e = blockIdx.x * blockDim.x + threadIdx.x; e < E; e += stride) {
    int src, dst;
    if (is64) { src = ei[2 * e]; dst = ei[2 * E + 2 * e]; }
    else      { src = ei[e];     dst = ei[E + e]; }
    if ((unsigned)src >= NNODES || (unsigned)dst >= NNODES) continue;
    int pos = rowptr[dst] + atomicAdd(&cursor[dst], 1);
    if ((unsigned)pos < (unsigned)E) srcs[pos] = src;   // bounds insurance
  }
}

// ---------------- gather-reduce: hpad[n] = bf16(x[n] + sum_{j in N(n)} x[j]) ----------------
// One wave per node; lane l owns feats [4l..4l+3] (8B of bf16). Pad rows -> 0.
__global__ __launch_bounds__(256) void gather_kernel(const u16* __restrict__ xbf,
                                                     const int* __restrict__ srcs,
                                                     const int* __restrict__ rowptr,
                                                     u16* __restrict__ hpad) {
  const int lane = threadIdx.x & 63;
  const int node = blockIdx.x * 4 + (threadIdx.x >> 6);
  if (node >= MPAD) return;
  ushort4* outp = (ushort4*)(hpad + (size_t)node * NF + lane * 4);
  if (node >= NNODES) {
    ushort4 z = {0, 0, 0, 0};
    *outp = z;
    return;
  }
  ushort4 sv = ((const ushort4*)(xbf + (size_t)node * NF))[lane];
  float4 acc;
  acc.x = bf2f(sv.x); acc.y = bf2f(sv.y); acc.z = bf2f(sv.z); acc.w = bf2f(sv.w);
  int e = rowptr[node];
  const int e1 = rowptr[node + 1];
  for (; e + 3 < e1; e += 4) {
    int s0 = srcs[e], s1 = srcs[e + 1], s2 = srcs[e + 2], s3 = srcs[e + 3];
    ushort4 v0 = ((const ushort4*)(xbf + (size_t)s0 * NF))[lane];
    ushort4 v1 = ((const ushort4*)(xbf + (size_t)s1 * NF))[lane];
    ushort4 v2 = ((const ushort4*)(xbf + (size_t)s2 * NF))[lane];
    ushort4 v3 = ((const ushort4*)(xbf + (size_t)s3 * NF))[lane];
    acc.x += bf2f(v0.x) + bf2f(v1.x) + bf2f(v2.x) + bf2f(v3.x);
    acc.y += bf2f(v0.y) + bf2f(v1.y) + bf2f(v2.y) + bf2f(v3.y);
    acc.z += bf2f(v0.z) + bf2f(v1.z) + bf2f(v2.z) + bf2f(v3.z);
    acc.w += bf2f(v0.w) + bf2f(v1.w) + bf2f(v2.w) + bf2f(v3.w);
  }
  for (; e < e1; ++e) {
    int s0 = srcs[e];
    ushort4 v0 = ((const ushort4*)(xbf + (size_t)s0 * NF))[lane];
    acc.x += bf2f(v0.x); acc.y += bf2f(v0.y); acc.z += bf2f(v0.z); acc.w += bf2f(v0.w);
  }
  ushort4 o;
  o.x = f2bf(acc.x); o.y = f2bf(acc.y); o.z = f2bf(acc.z); o.w = f2bf(acc.w);
  *outp = o;
}

// ---------------- W1t[n][k] = bf16(W1[k][n]), f32 source ----------------
__global__ __launch_bounds__(256) void transpose_w1(const float* __restrict__ W1,
                                                    u16* __restrict__ W1t) {
  int idx = blockIdx.x * 256 + threadIdx.x;   // 512*256 total
  int n = idx >> 8;
  int k = idx & 255;
  W1t[(size_t)n * NF + k] = f2bf(W1[(size_t)k * NH + n]);
}

// ---------------- GEMM: C[M][512] = A[M][K] * Bt[512][K]^T + bias ----------------
// SWAPPED-OPERAND MFMA: acc[n][m] = mfma(bfr[n], af[m], .) computes the transposed
// tile, so each lane's 4 regs are 4 CONSECUTIVE C-COLUMNS at one row -> vectorized
// float4/ushort4 epilogue stores (16 VMEM instrs/thread vs 64 scalar: the GEMMs
// were store-issue-bound; K-independence of duration proved it).
// T3 2-phase dbuf + pre-swizzled gload_lds source + swizzled ds_read + m204 XCD chunking.
template <int K, bool RELU, bool OUTF32>
__global__ __launch_bounds__(256) void gemm_bt(const u16* __restrict__ Ab,
                                               const u16* __restrict__ Bt,
                                               const float* __restrict__ bias,
                                               void* __restrict__ Cp, int Mstore) {
  __shared__ __align__(16) u16 As[2][128 * 64];
  __shared__ __align__(16) u16 Bs[2][128 * 64];
  const int tid = threadIdx.x;
  const int lane = tid & 63;
  const int wid = tid >> 6;
  const int wr = wid >> 1, wc = wid & 1;

  // m204 bijective XCD-chunked swizzle
  const int nwg = gridDim.x;
  const int q = nwg >> 3, r = nwg & 7;
  const int xcd = blockIdx.x & 7, idx = blockIdx.x >> 3;
  const int work = (xcd < r ? xcd * (q + 1) : r * (q + 1) + (xcd - r) * q) + idx;
  const int brow = (work >> 2) * 128;   // col-fastest: same-A blocks adjacent
  const int bcol = (work & 3) * 128;

  f32x4 acc[4][4] = {};   // acc[n][m] — transposed tile

  // gload_lds lane mapping: lane l -> LDS element chunkbase + l*8
  //   row-in-chunk = l>>3, swizzled k-slot cs = l&7 -> global kc = (cs ^ row&7)*8
  const int lrow = lane >> 3;
  const int lkc = ((lane & 7) ^ (lrow & 7)) * 8;

  const int nt = K / 64;

  // prologue: stage tile 0 into buffer 0
#pragma unroll
  for (int i = 0; i < 4; ++i) {
    int c = i * 4 + wid;
    int row = c * 8 + lrow;
    async16(Ab + (size_t)(brow + row) * K + lkc, &As[0][c * 512]);
    async16(Bt + (size_t)(bcol + row) * K + lkc, &Bs[0][c * 512]);
  }
  __syncthreads();

  int cur = 0;
  for (int t = 0; t < nt; ++t) {
    // issue next tile's loads FIRST (into the other buffer) — overlap with MFMA
    if (t + 1 < nt) {
      const int k0 = (t + 1) * 64;
#pragma unroll
      for (int i = 0; i < 4; ++i) {
        int c = i * 4 + wid;
        int row = c * 8 + lrow;
        async16(Ab + (size_t)(brow + row) * K + k0 + lkc, &As[cur ^ 1][c * 512]);
        async16(Bt + (size_t)(bcol + row) * K + k0 + lkc, &Bs[cur ^ 1][c * 512]);
      }
    }
    // compute current tile
#pragma unroll
    for (int ks = 0; ks < 2; ++ks) {
      bf16x8 af[4], bfr[4];
      const int rchunk = ((ks << 2) + (lane >> 4)) ^ (lane & 7);  // swizzled read slot
#pragma unroll
      for (int m = 0; m < 4; ++m)
        af[m] = *(const bf16x8*)&As[cur][(wr * 64 + m * 16 + (lane & 15)) * 64 + rchunk * 8];
#pragma unroll
      for (int n = 0; n < 4; ++n)
        bfr[n] = *(const bf16x8*)&Bs[cur][(wc * 64 + n * 16 + (lane & 15)) * 64 + rchunk * 8];
#pragma unroll
      for (int n = 0; n < 4; ++n)
#pragma unroll
        for (int m = 0; m < 4; ++m)
          acc[n][m] = __builtin_amdgcn_mfma_f32_16x16x32_bf16(bfr[n], af[m], acc[n][m], 0, 0, 0);
    }
    __syncthreads();   // drains prefetch vmcnt + all ds_reads; next iter flips buffers
    cur ^= 1;
  }

  // vectorized epilogue: lane holds 4 consecutive C-cols at one row per (n,m)
  const int row_base = brow + wr * 64 + (lane & 15);
  const int col_base = bcol + wc * 64 + ((lane >> 4) << 2);
#pragma unroll
  for (int n = 0; n < 4; ++n) {
    int col = col_base + n * 16;
    float4 bv4 = *(const float4*)&bias[col];
#pragma unroll
    for (int m = 0; m < 4; ++m) {
      int row = row_base + m * 16;
      if (row < Mstore) {
        f32x4 a = acc[n][m];
        float v0 = a[0] + bv4.x, v1 = a[1] + bv4.y, v2 = a[2] + bv4.z, v3 = a[3] + bv4.w;
        if (RELU) {
          v0 = fmaxf(v0, 0.f); v1 = fmaxf(v1, 0.f);
          v2 = fmaxf(v2, 0.f); v3 = fmaxf(v3, 0.f);
        }
        if (OUTF32) {
          float4 o = {v0, v1, v2, v3};
          *(float4*)&((float*)Cp)[(size_t)row * NH + col] = o;
        } else {
          ushort4 o = {f2bf(v0), f2bf(v1), f2bf(v2), f2bf(v3)};
          *(ushort4*)&((u16*)Cp)[(size_t)row * NH + col] = o;
        }
      }
    }
  }
}

// ---------------- stats stage 1: per-block column sums/sumsq, NO atomics ----------------
// partials[b][c]: c in [0,512) = sum, c in [512,1024) = sumsq.
__global__ __launch_bounds__(256) void stats1_kernel(const u16* __restrict__ h1,
                                                     float* __restrict__ partials) {
  const int tg = threadIdx.x & 63;     // column group: cols [8*tg, 8*tg+8)
  const int tr = threadIdx.x >> 6;     // row phase 0..3
  float s[8] = {}, q[8] = {};
  for (int r = blockIdx.x * 4 + tr; r < NNODES; r += SBLOCKS * 4) {
    bf16x8 v = *(const bf16x8*)(h1 + (size_t)r * NH + tg * 8);
#pragma unroll
    for (int j = 0; j < 8; ++j) {
      float f = bf2f((u16)v[j]);
      s[j] += f; q[j] += f * f;
    }
  }
  __shared__ float red_s[4][512];
  __shared__ float red_q[4][512];
#pragma unroll
  for (int j = 0; j < 8; ++j) {
    red_s[tr][tg * 8 + j] = s[j];
    red_q[tr][tg * 8 + j] = q[j];
  }
  __syncthreads();
  float* outp = partials + (size_t)blockIdx.x * 1024;
#pragma unroll
  for (int h = 0; h < 2; ++h) {
    int c = threadIdx.x + h * 256;
    outp[c]       = red_s[0][c] + red_s[1][c] + red_s[2][c] + red_s[3][c];
    outp[c + 512] = red_q[0][c] + red_q[1][c] + red_q[2][c] + red_q[3][c];
  }
}

// ---------------- stats stage 2: reduce partials over blocks (plain stores) ----------------
__global__ __launch_bounds__(256) void stats2_kernel(const float* __restrict__ partials,
                                                     float* __restrict__ ssum) {
  int c = blockIdx.x * 256 + threadIdx.x;   // 0..1023
  float acc = 0.f;
  for (int b = 0; b < SBLOCKS; ++b) acc += partials[(size_t)b * 1024 + c];
  ssum[c] = acc;
}

// ---------------- BN finalize + sanity check ----------------
__global__ void bn_finalize(const float* __restrict__ ssum, const float* __restrict__ ssq,
                            const float* __restrict__ gamma, const float* __restrict__ beta,
                            float* __restrict__ a_arr, float* __restrict__ c_arr,
                            int* __restrict__ err) {
  int c = threadIdx.x;  // 512 threads
  float mean = ssum[c] * (1.f / NNODES);
  float var = ssq[c] * (1.f / NNODES) - mean * mean;
  if (!(mean == mean) || !(var == var) ||
      fabsf(mean) > 1e20f || var > 1e20f || var < -1e-2f)
    err[0] = 2;
  unsigned long long z = __ballot(ssq[c] == 0.0f);
  if (threadIdx.x == 0 && z == ~0ull) err[1] = 3;
  if (var < 0.f) var = 0.f;
  float a = gamma[c] * rsqrtf(var + BN_EPS);
  a_arr[c] = a;
  c_arr[c] = beta[c] - mean * a;
}

// ---------------- fold BN into W2 ----------------
__global__ __launch_bounds__(256) void fold_w2(const float* __restrict__ W2,
                                               const float* __restrict__ b2,
                                               const float* __restrict__ a_arr,
                                               const float* __restrict__ c_arr,
                                               u16* __restrict__ W2pt,
                                               float* __restrict__ bias2p) {
  int n = blockIdx.x;
  int t = threadIdx.x;
  float accv = 0.f;
  for (int k = t; k < NH; k += 256) {
    float w = W2[(size_t)k * NH + n];
    W2pt[(size_t)n * NH + k] = f2bf(a_arr[k] * w);
    accv += c_arr[k] * w;
  }
  __shared__ float red[256];
  red[t] = accv;
  __syncthreads();
  for (int s = 128; s > 0; s >>= 1) {
    if (t < s) red[t] += red[t + s];
    __syncthreads();
  }
  if (t == 0) bias2p[n] = b2[n] + red[0];
}

// ---------------- diagnostics ----------------
__global__ __launch_bounds__(256) void write_sentinel(float* __restrict__ out, int n, float val) {
  int stride = gridDim.x * blockDim.x;
  for (int i = blockIdx.x * blockDim.x + threadIdx.x; i < n; i += stride) out[i] = val;
}

__global__ __launch_bounds__(256) void apply_err(const int* __restrict__ err,
                                                 float* __restrict__ out, int n) {
  float val = 0.f;
  if (err[1] == 3) val = -300000.f;
  if (err[0] == 2) val = -500000.f;
  if (val == 0.f) return;
  int stride = gridDim.x * blockDim.x;
  for (int i = blockIdx.x * blockDim.x + threadIdx.x; i < n; i += stride) out[i] = val;
}

extern "C" void kernel_launch(void* const* d_in, const int* in_sizes, int n_in,
                              void* d_out, int out_size, void* d_ws, size_t ws_size,
                              hipStream_t stream) {
  const float* x     = (const float*)d_in[0];
  const int*   ei    = (const int*)d_in[1];
  const float* W1    = (const float*)d_in[2];
  const float* b1    = (const float*)d_in[3];
  const float* gamma = (const float*)d_in[4];
  const float* beta  = (const float*)d_in[5];
  const float* W2    = (const float*)d_in[6];
  const float* b2    = (const float*)d_in[7];
  float* out = (float*)d_out;
  const int E = in_sizes[1] / 2;   // 800000

  char* ws = (char*)d_ws;
  size_t off = 0;
  auto alloc = [&](size_t bytes) {
    char* p = ws + off;
    off += (bytes + 255) & ~(size_t)255;
    return p;
  };
  u16*   xbf    = (u16*)alloc((size_t)NNODES * NF * 2);     // 25.6 MB
  u16*   hpad   = (u16*)alloc((size_t)MPAD * NF * 2);       // 25.6 MB
  u16*   h1     = (u16*)alloc((size_t)MPAD * NH * 2);       // 51.25 MB
  u16*   W1t    = (u16*)alloc((size_t)NH * NF * 2);
  u16*   W2pt   = (u16*)alloc((size_t)NH * NH * 2);
  int*   srcs   = (int*)alloc((size_t)E * 4);               // 3.2 MB
  int*   rowptr = (int*)alloc((size_t)(NNODES + 1) * 4);
  int*   deg    = (int*)alloc((size_t)2 * NNODES * 4);      // deg[0:N] + cursor[N:2N], ONE block
  int*   cursor = deg + NNODES;
  int*   bsums  = (int*)alloc(256 * 4);                     // scan block sums
  float* parts  = (float*)alloc((size_t)SBLOCKS * 1024 * 4);// 2 MB stats partials
  float* ssum   = (float*)alloc(NH * 4);   // ssum+ssq contiguous (stats2 writes both)
  float* ssq    = (float*)alloc(NH * 4);
  int*   err    = (int*)alloc(8);
  float* a_arr  = (float*)alloc(NH * 4);
  float* c_arr  = (float*)alloc(NH * 4);
  float* bias2p = (float*)alloc(NH * 4);
  int*   flag   = (int*)alloc(4);

  if (off > ws_size) {
    write_sentinel<<<2048, 256, 0, stream>>>(out, out_size,
        1.0e7f + 1048576.0f * (float)(ws_size >> 20));
    return;
  }

  hipMemsetAsync(deg, 0, (size_t)2 * NNODES * 4, stream);   // deg + cursor (contiguous)
  hipMemsetAsync(err, 0, 8, stream);

  detect_idx<<<1, 64, 0, stream>>>(ei, flag);
  conv_x<<<2048, 256, 0, stream>>>(x, xbf);
  hist_kernel<<<1024, 256, 0, stream>>>(ei, flag, deg, E);
  scan1_kernel<<<NSCAN, 256, 0, stream>>>(deg, rowptr, bsums);
  scan2_kernel<<<1, 256, 0, stream>>>(bsums, rowptr);
  scan3_kernel<<<NSCAN, 256, 0, stream>>>(bsums, rowptr);
  fill_kernel<<<1024, 256, 0, stream>>>(ei, flag, rowptr, cursor, srcs, E);
  gather_kernel<<<MPAD / 4, 256, 0, stream>>>(xbf, srcs, rowptr, hpad);

  transpose_w1<<<512, 256, 0, stream>>>(W1, W1t);

  const int nwg = (MPAD / 128) * 4;   // 1564, 1-D grid (col-fastest + XCD chunking)
  gemm_bt<NF, true, false><<<nwg, 256, 0, stream>>>(hpad, W1t, b1, h1, MPAD);

  stats1_kernel<<<SBLOCKS, 256, 0, stream>>>(h1, parts);
  stats2_kernel<<<4, 256, 0, stream>>>(parts, ssum);
  bn_finalize<<<1, NH, 0, stream>>>(ssum, ssq, gamma, beta, a_arr, c_arr, err);
  fold_w2<<<NH, 256, 0, stream>>>(W2, b2, a_arr, c_arr, W2pt, bias2p);

  gemm_bt<NH, false, true><<<nwg, 256, 0, stream>>>(h1, W2pt, bias2p, out, NNODES);

  apply_err<<<2048, 256, 0, stream>>>(err, out, out_size);
}

// Round 14
// 283.282 us; speedup vs baseline: 1.1690x; 1.0909x over previous
//
#include <hip/hip_runtime.h>

#define NNODES 50000
#define NF 256
#define NH 512
#define MPAD 50048   // 391 * 128
#define NRB 391      // MPAD/128 row-blocks
#define BN_EPS 1e-5f
#define NSCAN 196    // ceil(NNODES/256)

typedef unsigned short u16;
typedef __attribute__((ext_vector_type(8))) short bf16x8;
typedef __attribute__((ext_vector_type(4))) float f32x4;

__device__ __forceinline__ float bf2f(u16 u) {
  union { unsigned int i; float f; } v; v.i = ((unsigned int)u) << 16; return v.f;
}
__device__ __forceinline__ u16 f2bf(float f) {
  union { float ff; unsigned int i; } v; v.ff = f;
  unsigned int r = v.i + 0x7FFFu + ((v.i >> 16) & 1u);
  return (u16)(r >> 16);
}

__device__ __forceinline__ void async16(const void* g, void* l) {
  __builtin_amdgcn_global_load_lds(
      (const __attribute__((address_space(1))) unsigned int*)g,
      (__attribute__((address_space(3))) unsigned int*)l, 16, 0, 0);
}

// ---------------- edge-index dtype probe ----------------
__global__ void detect_idx(const int* __restrict__ ei, int* __restrict__ flag) {
  int v = ei[2 * threadIdx.x + 1];
  unsigned long long b = __ballot(v == 0);
  if (threadIdx.x == 0) *flag = (b == ~0ull) ? 1 : 0;
}

// ---------------- fused prep: conv_x (blocks 0..2047) + transpose_w1 (2048..2559)
//                  + hist (2560..3583) — mutually independent work ----------------
__global__ __launch_bounds__(256) void prep_kernel(const float* __restrict__ x,
                                                   u16* __restrict__ xbf,
                                                   const float* __restrict__ W1,
                                                   u16* __restrict__ W1t,
                                                   const int* __restrict__ ei,
                                                   const int* __restrict__ flag,
                                                   int* __restrict__ deg, int E) {
  const int b = blockIdx.x;
  if (b < 2048) {
    // conv_x: xbf = bf16(x)
    const size_t n8 = (size_t)NNODES * NF / 8;
    size_t stride = (size_t)2048 * 256;
    for (size_t i = b * (size_t)256 + threadIdx.x; i < n8; i += stride) {
      float4 a = ((const float4*)x)[2 * i];
      float4 c = ((const float4*)x)[2 * i + 1];
      ushort4 lo, hi;
      lo.x = f2bf(a.x); lo.y = f2bf(a.y); lo.z = f2bf(a.z); lo.w = f2bf(a.w);
      hi.x = f2bf(c.x); hi.y = f2bf(c.y); hi.z = f2bf(c.z); hi.w = f2bf(c.w);
      ((ushort4*)xbf)[2 * i] = lo;
      ((ushort4*)xbf)[2 * i + 1] = hi;
    }
  } else if (b < 2560) {
    // transpose_w1: W1t[n][k] = bf16(W1[k][n])
    int idx = (b - 2048) * 256 + threadIdx.x;
    int n = idx >> 8;
    int k = idx & 255;
    W1t[(size_t)n * NF + k] = f2bf(W1[(size_t)k * NH + n]);
  } else {
    // hist: deg histogram over dst, vectorized int4 reads
    const int is64 = *flag;
    const int gtid = (b - 2560) * 256 + threadIdx.x;
    const int stride = 1024 * 256;
    if (is64) {
      const int4* d4 = (const int4*)(ei + 2 * (size_t)E);   // 2 edges per int4
      int np = E >> 1;
      for (int p = gtid; p < np; p += stride) {
        int4 d = d4[p];
        if ((unsigned)d.x < NNODES) atomicAdd(&deg[d.x], 1);
        if ((unsigned)d.z < NNODES) atomicAdd(&deg[d.z], 1);
      }
      for (int e = (np << 1) + gtid; e < E; e += stride) {
        int d = ei[2 * (size_t)E + 2 * e];
        if ((unsigned)d < NNODES) atomicAdd(&deg[d], 1);
      }
    } else {
      const int4* d4 = (const int4*)(ei + E);               // 4 edges per int4
      int np = E >> 2;
      for (int p = gtid; p < np; p += stride) {
        int4 d = d4[p];
        if ((unsigned)d.x < NNODES) atomicAdd(&deg[d.x], 1);
        if ((unsigned)d.y < NNODES) atomicAdd(&deg[d.y], 1);
        if ((unsigned)d.z < NNODES) atomicAdd(&deg[d.z], 1);
        if ((unsigned)d.w < NNODES) atomicAdd(&deg[d.w], 1);
      }
      for (int e = (np << 2) + gtid; e < E; e += stride) {
        int d = ei[(size_t)E + e];
        if ((unsigned)d < NNODES) atomicAdd(&deg[d], 1);
      }
    }
  }
}

// ---------------- CSR build: 3-phase parallel exclusive scan ----------------
__global__ __launch_bounds__(256) void scan1_kernel(const int* __restrict__ deg,
                                                    int* __restrict__ rowptr,
                                                    int* __restrict__ blocksums) {
  const int t = threadIdx.x;
  int i = blockIdx.x * 256 + t;
  int v = (i < NNODES) ? deg[i] : 0;
  __shared__ int sm[256];
  sm[t] = v;
  __syncthreads();
  for (int off = 1; off < 256; off <<= 1) {
    int u = (t >= off) ? sm[t - off] : 0;
    __syncthreads();
    sm[t] += u;
    __syncthreads();
  }
  if (i < NNODES) rowptr[i] = sm[t] - v;
  if (t == 255) blocksums[blockIdx.x] = sm[255];
}

__global__ __launch_bounds__(256) void scan2_kernel(int* __restrict__ blocksums,
                                                    int* __restrict__ rowptr) {
  const int t = threadIdx.x;
  int v = (t < NSCAN) ? blocksums[t] : 0;
  __shared__ int sm[256];
  sm[t] = v;
  __syncthreads();
  for (int off = 1; off < 256; off <<= 1) {
    int u = (t >= off) ? sm[t - off] : 0;
    __syncthreads();
    sm[t] += u;
    __syncthreads();
  }
  if (t < NSCAN) blocksums[t] = sm[t] - v;
  if (t == 255) rowptr[NNODES] = sm[255];
}

__global__ __launch_bounds__(256) void scan3_kernel(const int* __restrict__ blocksums,
                                                    int* __restrict__ rowptr) {
  int i = blockIdx.x * 256 + threadIdx.x;
  if (i < NNODES) rowptr[i] += blocksums[blockIdx.x];
}

// ---------------- CSR build: fill src lists (vectorized int4 reads) ----------------
__global__ __launch_bounds__(256) void fill_kernel(const int* __restrict__ ei,
                                                   const int* __restrict__ flag,
                                                   const int* __restrict__ rowptr,
                                                   int* __restrict__ cursor,
                                                   int* __restrict__ srcs, int E) {
  const int is64 = *flag;
  const int gtid = blockIdx.x * 256 + threadIdx.x;
  const int stride = gridDim.x * 256;
  if (is64) {
    const int4* s4 = (const int4*)ei;                 // edges 2p,2p+1: .x,.z
    const int4* d4 = (const int4*)(ei + 2 * (size_t)E);
    int np = E >> 1;
    for (int p = gtid; p < np; p += stride) {
      int4 sv = s4[p], dv = d4[p];
      if ((unsigned)sv.x < NNODES && (unsigned)dv.x < NNODES) {
        int pos = rowptr[dv.x] + atomicAdd(&cursor[dv.x], 1);
        if ((unsigned)pos < (unsigned)E) srcs[pos] = sv.x;
      }
      if ((unsigned)sv.z < NNODES && (unsigned)dv.z < NNODES) {
        int pos = rowptr[dv.z] + atomicAdd(&cursor[dv.z], 1);
        if ((unsigned)pos < (unsigned)E) srcs[pos] = sv.z;
      }
    }
    for (int e = (np << 1) + gtid; e < E; e += stride) {
      int src = ei[2 * e], dst = ei[2 * (size_t)E + 2 * e];
      if ((unsigned)src >= NNODES || (unsigned)dst >= NNODES) continue;
      int pos = rowptr[dst] + atomicAdd(&cursor[dst], 1);
      if ((unsigned)pos < (unsigned)E) srcs[pos] = src;
    }
  } else {
    const int4* s4 = (const int4*)ei;                 // 4 edges per int4
    const int4* d4 = (const int4*)(ei + E);
    int np = E >> 2;
    for (int p = gtid; p < np; p += stride) {
      int4 sv = s4[p], dv = d4[p];
      int ss[4] = {sv.x, sv.y, sv.z, sv.w};
      int dd[4] = {dv.x, dv.y, dv.z, dv.w};
#pragma unroll
      for (int j = 0; j < 4; ++j) {
        if ((unsigned)ss[j] < NNODES && (unsigned)dd[j] < NNODES) {
          int pos = rowptr[dd[j]] + atomicAdd(&cursor[dd[j]], 1);
          if ((unsigned)pos < (unsigned)E) srcs[pos] = ss[j];
        }
      }
    }
    for (int e = (np << 2) + gtid; e < E; e += stride) {
      int src = ei[e], dst = ei[(size_t)E + e];
      if ((unsigned)src >= NNODES || (unsigned)dst >= NNODES) continue;
      int pos = rowptr[dst] + atomicAdd(&cursor[dst], 1);
      if ((unsigned)pos < (unsigned)E) srcs[pos] = src;
    }
  }
}

// ---------------- gather-reduce: hpad[n] = bf16(x[n] + sum_{j in N(n)} x[j]) ----------------
__global__ __launch_bounds__(256) void gather_kernel(const u16* __restrict__ xbf,
                                                     const int* __restrict__ srcs,
                                                     const int* __restrict__ rowptr,
                                                     u16* __restrict__ hpad) {
  const int lane = threadIdx.x & 63;
  const int node = blockIdx.x * 4 + (threadIdx.x >> 6);
  if (node >= MPAD) return;
  ushort4* outp = (ushort4*)(hpad + (size_t)node * NF + lane * 4);
  if (node >= NNODES) {
    ushort4 z = {0, 0, 0, 0};
    *outp = z;
    return;
  }
  ushort4 sv = ((const ushort4*)(xbf + (size_t)node * NF))[lane];
  float4 acc;
  acc.x = bf2f(sv.x); acc.y = bf2f(sv.y); acc.z = bf2f(sv.z); acc.w = bf2f(sv.w);
  int e = rowptr[node];
  const int e1 = rowptr[node + 1];
  for (; e + 3 < e1; e += 4) {
    int s0 = srcs[e], s1 = srcs[e + 1], s2 = srcs[e + 2], s3 = srcs[e + 3];
    ushort4 v0 = ((const ushort4*)(xbf + (size_t)s0 * NF))[lane];
    ushort4 v1 = ((const ushort4*)(xbf + (size_t)s1 * NF))[lane];
    ushort4 v2 = ((const ushort4*)(xbf + (size_t)s2 * NF))[lane];
    ushort4 v3 = ((const ushort4*)(xbf + (size_t)s3 * NF))[lane];
    acc.x += bf2f(v0.x) + bf2f(v1.x) + bf2f(v2.x) + bf2f(v3.x);
    acc.y += bf2f(v0.y) + bf2f(v1.y) + bf2f(v2.y) + bf2f(v3.y);
    acc.z += bf2f(v0.z) + bf2f(v1.z) + bf2f(v2.z) + bf2f(v3.z);
    acc.w += bf2f(v0.w) + bf2f(v1.w) + bf2f(v2.w) + bf2f(v3.w);
  }
  for (; e < e1; ++e) {
    int s0 = srcs[e];
    ushort4 v0 = ((const ushort4*)(xbf + (size_t)s0 * NF))[lane];
    acc.x += bf2f(v0.x); acc.y += bf2f(v0.y); acc.z += bf2f(v0.z); acc.w += bf2f(v0.w);
  }
  ushort4 o;
  o.x = f2bf(acc.x); o.y = f2bf(acc.y); o.z = f2bf(acc.z); o.w = f2bf(acc.w);
  *outp = o;
}

// ---------------- GEMM: C[M][512] = A[M][K] * Bt[512][K]^T + bias ----------------
// Swapped-operand MFMA (vectorized stores) + T3 dbuf + pre-swizzled gload_lds +
// m204 XCD chunking. STATS: fuse BN column sum/sumsq partials into the epilogue
// (rows < NNODES only), written to parts[work][256] (128 sum + 128 sumsq).
template <int K, bool RELU, bool OUTF32, bool STATS>
__global__ __launch_bounds__(256) void gemm_bt(const u16* __restrict__ Ab,
                                               const u16* __restrict__ Bt,
                                               const float* __restrict__ bias,
                                               void* __restrict__ Cp, int Mstore,
                                               float* __restrict__ parts) {
  __shared__ __align__(16) u16 As[2][128 * 64];
  __shared__ __align__(16) u16 Bs[2][128 * 64];
  __shared__ float sred[256];
  const int tid = threadIdx.x;
  const int lane = tid & 63;
  const int wid = tid >> 6;
  const int wr = wid >> 1, wc = wid & 1;

  const int nwg = gridDim.x;
  const int q = nwg >> 3, r = nwg & 7;
  const int xcd = blockIdx.x & 7, idx = blockIdx.x >> 3;
  const int work = (xcd < r ? xcd * (q + 1) : r * (q + 1) + (xcd - r) * q) + idx;
  const int brow = (work >> 2) * 128;
  const int bcol = (work & 3) * 128;

  f32x4 acc[4][4] = {};   // acc[n][m] — transposed tile

  const int lrow = lane >> 3;
  const int lkc = ((lane & 7) ^ (lrow & 7)) * 8;
  const int nt = K / 64;

#pragma unroll
  for (int i = 0; i < 4; ++i) {
    int c = i * 4 + wid;
    int row = c * 8 + lrow;
    async16(Ab + (size_t)(brow + row) * K + lkc, &As[0][c * 512]);
    async16(Bt + (size_t)(bcol + row) * K + lkc, &Bs[0][c * 512]);
  }
  if (STATS) {
    if (tid < 64) ((float4*)sred)[tid] = (float4){0.f, 0.f, 0.f, 0.f};
  }
  __syncthreads();

  int cur = 0;
  for (int t = 0; t < nt; ++t) {
    if (t + 1 < nt) {
      const int k0 = (t + 1) * 64;
#pragma unroll
      for (int i = 0; i < 4; ++i) {
        int c = i * 4 + wid;
        int row = c * 8 + lrow;
        async16(Ab + (size_t)(brow + row) * K + k0 + lkc, &As[cur ^ 1][c * 512]);
        async16(Bt + (size_t)(bcol + row) * K + k0 + lkc, &Bs[cur ^ 1][c * 512]);
      }
    }
#pragma unroll
    for (int ks = 0; ks < 2; ++ks) {
      bf16x8 af[4], bfr[4];
      const int rchunk = ((ks << 2) + (lane >> 4)) ^ (lane & 7);
#pragma unroll
      for (int m = 0; m < 4; ++m)
        af[m] = *(const bf16x8*)&As[cur][(wr * 64 + m * 16 + (lane & 15)) * 64 + rchunk * 8];
#pragma unroll
      for (int n = 0; n < 4; ++n)
        bfr[n] = *(const bf16x8*)&Bs[cur][(wc * 64 + n * 16 + (lane & 15)) * 64 + rchunk * 8];
#pragma unroll
      for (int n = 0; n < 4; ++n)
#pragma unroll
        for (int m = 0; m < 4; ++m)
          acc[n][m] = __builtin_amdgcn_mfma_f32_16x16x32_bf16(bfr[n], af[m], acc[n][m], 0, 0, 0);
    }
    __syncthreads();
    cur ^= 1;
  }

  // epilogue: lane holds 4 consecutive C-cols at one row per (n,m)
  const int row_base = brow + wr * 64 + (lane & 15);
  const int col_base = bcol + wc * 64 + ((lane >> 4) << 2);
#pragma unroll
  for (int n = 0; n < 4; ++n) {
    int col = col_base + n * 16;
    float4 bv4 = *(const float4*)&bias[col];
    float s0 = 0.f, s1 = 0.f, s2 = 0.f, s3 = 0.f;
    float q0 = 0.f, q1 = 0.f, q2 = 0.f, q3 = 0.f;
#pragma unroll
    for (int m = 0; m < 4; ++m) {
      int row = row_base + m * 16;
      f32x4 a = acc[n][m];
      float v0 = a[0] + bv4.x, v1 = a[1] + bv4.y, v2 = a[2] + bv4.z, v3 = a[3] + bv4.w;
      if (RELU) {
        v0 = fmaxf(v0, 0.f); v1 = fmaxf(v1, 0.f);
        v2 = fmaxf(v2, 0.f); v3 = fmaxf(v3, 0.f);
      }
      if (row < Mstore) {
        if (OUTF32) {
          float4 o = {v0, v1, v2, v3};
          *(float4*)&((float*)Cp)[(size_t)row * NH + col] = o;
        } else {
          ushort4 o = {f2bf(v0), f2bf(v1), f2bf(v2), f2bf(v3)};
          *(ushort4*)&((u16*)Cp)[(size_t)row * NH + col] = o;
        }
      }
      if (STATS && row < NNODES) {
        s0 += v0; s1 += v1; s2 += v2; s3 += v3;
        q0 += v0 * v0; q1 += v1 * v1; q2 += v2 * v2; q3 += v3 * v3;
      }
    }
    if (STATS) {
      // reduce over lane bits 0..3 (the 16 row-lanes sharing this col quad)
#pragma unroll
      for (int msk = 1; msk < 16; msk <<= 1) {
        s0 += __shfl_xor(s0, msk); s1 += __shfl_xor(s1, msk);
        s2 += __shfl_xor(s2, msk); s3 += __shfl_xor(s3, msk);
        q0 += __shfl_xor(q0, msk); q1 += __shfl_xor(q1, msk);
        q2 += __shfl_xor(q2, msk); q3 += __shfl_xor(q3, msk);
      }
      if ((lane & 15) == 0) {
        int lc = wc * 64 + n * 16 + ((lane >> 4) << 2);
        atomicAdd(&sred[lc + 0], s0); atomicAdd(&sred[lc + 1], s1);
        atomicAdd(&sred[lc + 2], s2); atomicAdd(&sred[lc + 3], s3);
        atomicAdd(&sred[128 + lc + 0], q0); atomicAdd(&sred[128 + lc + 1], q1);
        atomicAdd(&sred[128 + lc + 2], q2); atomicAdd(&sred[128 + lc + 3], q3);
      }
    }
  }
  if (STATS) {
    __syncthreads();
    if (tid < 128) {
      parts[(size_t)work * 256 + tid] = sred[tid];
      parts[(size_t)work * 256 + 128 + tid] = sred[128 + tid];
    }
  }
}

// ---------------- stats2: reduce per-block partials -> ssum[0:512)=sum, [512:1024)=sumsq
__global__ __launch_bounds__(256) void stats2_kernel(const float* __restrict__ parts,
                                                     float* __restrict__ ssum) {
  int c = blockIdx.x * 256 + threadIdx.x;   // 0..1023
  int c0 = c & 511, issq = c >> 9;
  float acc = 0.f;
  for (int rb = 0; rb < NRB; ++rb)
    acc += parts[(size_t)((rb << 2) + (c0 >> 7)) * 256 + (c0 & 127) + (issq ? 128 : 0)];
  ssum[c] = acc;
}

// ---------------- BN finalize + sanity check ----------------
__global__ void bn_finalize(const float* __restrict__ ssum, const float* __restrict__ ssq,
                            const float* __restrict__ gamma, const float* __restrict__ beta,
                            float* __restrict__ a_arr, float* __restrict__ c_arr,
                            int* __restrict__ err) {
  int c = threadIdx.x;  // 512 threads
  float mean = ssum[c] * (1.f / NNODES);
  float var = ssq[c] * (1.f / NNODES) - mean * mean;
  if (!(mean == mean) || !(var == var) ||
      fabsf(mean) > 1e20f || var > 1e20f || var < -1e-2f)
    err[0] = 2;
  unsigned long long z = __ballot(ssq[c] == 0.0f);
  if (threadIdx.x == 0 && z == ~0ull) err[1] = 3;
  if (var < 0.f) var = 0.f;
  float a = gamma[c] * rsqrtf(var + BN_EPS);
  a_arr[c] = a;
  c_arr[c] = beta[c] - mean * a;
}

// ---------------- fold BN into W2 ----------------
__global__ __launch_bounds__(256) void fold_w2(const float* __restrict__ W2,
                                               const float* __restrict__ b2,
                                               const float* __restrict__ a_arr,
                                               const float* __restrict__ c_arr,
                                               u16* __restrict__ W2pt,
                                               float* __restrict__ bias2p) {
  int n = blockIdx.x;
  int t = threadIdx.x;
  float accv = 0.f;
  for (int k = t; k < NH; k += 256) {
    float w = W2[(size_t)k * NH + n];
    W2pt[(size_t)n * NH + k] = f2bf(a_arr[k] * w);
    accv += c_arr[k] * w;
  }
  __shared__ float red[256];
  red[t] = accv;
  __syncthreads();
  for (int s = 128; s > 0; s >>= 1) {
    if (t < s) red[t] += red[t + s];
    __syncthreads();
  }
  if (t == 0) bias2p[n] = b2[n] + red[0];
}

// ---------------- diagnostics ----------------
__global__ __launch_bounds__(256) void write_sentinel(float* __restrict__ out, int n, float val) {
  int stride = gridDim.x * blockDim.x;
  for (int i = blockIdx.x * blockDim.x + threadIdx.x; i < n; i += stride) out[i] = val;
}

__global__ __launch_bounds__(256) void apply_err(const int* __restrict__ err,
                                                 float* __restrict__ out, int n) {
  float val = 0.f;
  if (err[1] == 3) val = -300000.f;
  if (err[0] == 2) val = -500000.f;
  if (val == 0.f) return;
  int stride = gridDim.x * blockDim.x;
  for (int i = blockIdx.x * blockDim.x + threadIdx.x; i < n; i += stride) out[i] = val;
}

extern "C" void kernel_launch(void* const* d_in, const int* in_sizes, int n_in,
                              void* d_out, int out_size, void* d_ws, size_t ws_size,
                              hipStream_t stream) {
  const float* x     = (const float*)d_in[0];
  const int*   ei    = (const int*)d_in[1];
  const float* W1    = (const float*)d_in[2];
  const float* b1    = (const float*)d_in[3];
  const float* gamma = (const float*)d_in[4];
  const float* beta  = (const float*)d_in[5];
  const float* W2    = (const float*)d_in[6];
  const float* b2    = (const float*)d_in[7];
  float* out = (float*)d_out;
  const int E = in_sizes[1] / 2;   // 800000

  char* ws = (char*)d_ws;
  size_t off = 0;
  auto alloc = [&](size_t bytes) {
    char* p = ws + off;
    off += (bytes + 255) & ~(size_t)255;
    return p;
  };
  u16*   xbf    = (u16*)alloc((size_t)NNODES * NF * 2);     // 25.6 MB
  u16*   hpad   = (u16*)alloc((size_t)MPAD * NF * 2);       // 25.6 MB
  u16*   h1     = (u16*)alloc((size_t)MPAD * NH * 2);       // 51.25 MB
  u16*   W1t    = (u16*)alloc((size_t)NH * NF * 2);
  u16*   W2pt   = (u16*)alloc((size_t)NH * NH * 2);
  int*   srcs   = (int*)alloc((size_t)E * 4);               // 3.2 MB
  int*   rowptr = (int*)alloc((size_t)(NNODES + 1) * 4);
  int*   deg    = (int*)alloc((size_t)2 * NNODES * 4);      // deg + cursor, ONE block
  int*   cursor = deg + NNODES;
  int*   bsums  = (int*)alloc(256 * 4);
  float* parts  = (float*)alloc((size_t)NRB * 4 * 256 * 4); // 1.6 MB gemm1 stats partials
  float* ssum   = (float*)alloc(NH * 4);   // ssum+ssq contiguous (stats2 writes both)
  float* ssq    = (float*)alloc(NH * 4);
  int*   err    = (int*)alloc(8);
  float* a_arr  = (float*)alloc(NH * 4);
  float* c_arr  = (float*)alloc(NH * 4);
  float* bias2p = (float*)alloc(NH * 4);
  int*   flag   = (int*)alloc(4);

  if (off > ws_size) {
    write_sentinel<<<2048, 256, 0, stream>>>(out, out_size,
        1.0e7f + 1048576.0f * (float)(ws_size >> 20));
    return;
  }

  hipMemsetAsync(deg, 0, (size_t)2 * NNODES * 4, stream);
  hipMemsetAsync(err, 0, 8, stream);

  detect_idx<<<1, 64, 0, stream>>>(ei, flag);
  prep_kernel<<<3584, 256, 0, stream>>>(x, xbf, W1, W1t, ei, flag, deg, E);
  scan1_kernel<<<NSCAN, 256, 0, stream>>>(deg, rowptr, bsums);
  scan2_kernel<<<1, 256, 0, stream>>>(bsums, rowptr);
  scan3_kernel<<<NSCAN, 256, 0, stream>>>(bsums, rowptr);
  fill_kernel<<<1024, 256, 0, stream>>>(ei, flag, rowptr, cursor, srcs, E);
  gather_kernel<<<MPAD / 4, 256, 0, stream>>>(xbf, srcs, rowptr, hpad);

  const int nwg = NRB * 4;   // 1564
  gemm_bt<NF, true, false, true><<<nwg, 256, 0, stream>>>(hpad, W1t, b1, h1, MPAD, parts);

  stats2_kernel<<<4, 256, 0, stream>>>(parts, ssum);
  bn_finalize<<<1, NH, 0, stream>>>(ssum, ssq, gamma, beta, a_arr, c_arr, err);
  fold_w2<<<NH, 256, 0, stream>>>(W2, b2, a_arr, c_arr, W2pt, bias2p);

  gemm_bt<NH, false, true, false><<<nwg, 256, 0, stream>>>(h1, W2pt, bias2p, out, NNODES, nullptr);

  apply_err<<<2048, 256, 0, stream>>>(err, out, out_size);
}